// Round 8
// baseline (325.818 us; speedup 1.0000x reference)
//
#include <hip/hip_runtime.h>

typedef unsigned short u16;
typedef unsigned int   u32;

typedef __attribute__((ext_vector_type(8))) short short8;
typedef __attribute__((ext_vector_type(4))) float floatx4;

// ---- f32 -> bf16 (RNE) ----
__device__ __forceinline__ u16 f2bf(float f) {
    u32 u = __float_as_uint(f);
    u = u + 0x7fffu + ((u >> 16) & 1u);
    return (u16)(u >> 16);
}

__device__ __forceinline__ float bflo(u32 w) { return __uint_as_float(w << 16); }
__device__ __forceinline__ float bfhi(u32 w) { return __uint_as_float(w & 0xffff0000u); }

// pack two f32 -> two bf16 (round-to-nearest-away) in one v_perm
__device__ __forceinline__ u32 pack2bf(float s0, float s1) {
    u32 a = __float_as_uint(s0) + 0x8000u;
    u32 b = __float_as_uint(s1) + 0x8000u;
    return __builtin_amdgcn_perm(b, a, 0x07060302u);  // {bf(s1), bf(s0)}
}

__device__ __forceinline__ floatx4 mfma16(short8 a, short8 b, floatx4 c) {
    return __builtin_amdgcn_mfma_f32_16x16x32_bf16(a, b, c, 0, 0, 0);
}

// ---- prep: LDS-transpose weight tiles into per-thread MFMA B-fragment streams;
// block 80 zeroes accum + done-counter.
__global__ __launch_bounds__(256) void k_prep(
    const float* __restrict__ W1, const float* __restrict__ W2,
    const float* __restrict__ W3, u16* __restrict__ W1frag,
    u16* __restrict__ W2frag, u16* __restrict__ W3frag,
    float* __restrict__ accum, u32* __restrict__ counter) {
    __shared__ float ws[32][257];
    const int t = threadIdx.x;
    const int mode = blockIdx.x;
    const int lane = t & 63, grp = t >> 6;
    const int lr = lane & 15, lq = lane >> 4;

    if (mode < 64) {            // W1 tile kt=mode
        const int kt = mode;
#pragma unroll
        for (int i = 0; i < 32; ++i) {
            int idx2 = t + i * 256;
            ws[idx2 >> 8][idx2 & 255] = W1[(7 + kt * 32 + (idx2 >> 8)) * 256 + (idx2 & 255)];
        }
        __syncthreads();
        u16 arr[32];
#pragma unroll
        for (int f = 0; f < 4; ++f)
#pragma unroll
            for (int ji = 0; ji < 8; ++ji)
                arr[f * 8 + ji] = f2bf(ws[lq * 8 + ji][grp * 64 + f * 16 + lr]);
        uint4* dst = (uint4*)(W1frag + kt * 8192 + t * 32);
#pragma unroll
        for (int q = 0; q < 4; ++q) dst[q] = ((const uint4*)arr)[q];
    } else if (mode < 72) {     // W2 tile
        const int kt = mode - 64;
#pragma unroll
        for (int i = 0; i < 32; ++i) {
            int idx2 = t + i * 256;
            ws[idx2 >> 8][idx2 & 255] = W2[(kt * 32 + (idx2 >> 8)) * 256 + (idx2 & 255)];
        }
        __syncthreads();
        u16 arr[32];
#pragma unroll
        for (int f = 0; f < 4; ++f)
#pragma unroll
            for (int ji = 0; ji < 8; ++ji)
                arr[f * 8 + ji] = f2bf(ws[lq * 8 + ji][grp * 64 + f * 16 + lr]);
        uint4* dst = (uint4*)(W2frag + kt * 8192 + t * 32);
#pragma unroll
        for (int q = 0; q < 4; ++q) dst[q] = ((const uint4*)arr)[q];
    } else if (mode < 80) {     // W3 tile
        const int kt = mode - 72;
#pragma unroll
        for (int i = 0; i < 16; ++i) {
            int idx2 = t + i * 256;
            ws[idx2 >> 7][idx2 & 127] = W3[(kt * 32 + (idx2 >> 7)) * 128 + (idx2 & 127)];
        }
        __syncthreads();
        u16 arr[16];
#pragma unroll
        for (int j = 0; j < 2; ++j)
#pragma unroll
            for (int ji = 0; ji < 8; ++ji)
                arr[j * 8 + ji] = f2bf(ws[lq * 8 + ji][grp * 32 + j * 16 + lr]);
        uint4* dst = (uint4*)(W3frag + kt * 4096 + t * 16);
        dst[0] = ((const uint4*)arr)[0];
        dst[1] = ((const uint4*)arr)[1];
    } else {                    // zero accum + counter
#pragma unroll
        for (int i = 0; i < 24; ++i) accum[t + i * 256] = 0.f;
        if (t == 0) *counter = 0u;
    }
}

// ---- kernel 1: h1 = lrelu( [u,norm,proj,dots] @ W1 + b1 )
// 1024 thr (16 waves), M=64 x N=256 per block; wave (m4,n4) owns 16 rows x 64 cols.
// acc[4] = 16 AGPR -> <=64 regs/thread -> 8 waves/SIMD (32 waves/CU with 2 blocks).
// Dots tile frag-linear in LDS; gen = 2 dots/thread, lane-consecutive u32 write.
// xj coords bf16 SoA (all dot terms >=0: relative error only, no cancellation).
__global__ __launch_bounds__(1024, 8) void k_h1(
    const float* __restrict__ x, const float* __restrict__ u,
    const float* __restrict__ basis, const float* __restrict__ W1,
    const float* __restrict__ b1, const u16* __restrict__ W1frag,
    u16* __restrict__ h1) {
    __shared__ __align__(16) u16 xbf[6144];   // 12 KB bf16 SoA: X|Y|Z
    __shared__ __align__(16) u16 As[2][2048]; // 8 KB double-buffered dots tile
    __shared__ float rowsml[64][6];
    __shared__ float colsml[256][6];

    const int t = threadIdx.x;
    const int b = blockIdx.y;
    const int i0 = blockIdx.x * 64;
    const int lane = t & 63, wv = t >> 6;
    const int lr = lane & 15, lq = lane >> 4;
    const int m4 = wv >> 2, n4 = wv & 3;

    // bf16 SoA build (coalesced float4 global read, scalar LDS scatter)
    {
        const float4* src = (const float4*)(x + b * 6144);
#pragma unroll
        for (int kk = 0; kk < 2; ++kk) {
            int q = t + kk * 1024;
            if (q < 1536) {
                float4 v = src[q];
                float vv[4] = {v.x, v.y, v.z, v.w};
                int e = q * 4;
#pragma unroll
                for (int cc = 0; cc < 4; ++cc) {
                    int ee = e + cc;
                    xbf[(ee % 3) * 2048 + ee / 3] = f2bf(vv[cc]);
                }
            }
        }
    }
    if (t < 256) {
        int c = t;
        float u0 = u[b * 2 + 0], u1 = u[b * 2 + 1];
        colsml[c][0] = b1[c] + u0 * W1[c] + u1 * W1[256 + c];
        colsml[c][1] = W1[512 + c];
        colsml[c][2] = W1[768 + c];
        colsml[c][3] = W1[1024 + c];
        colsml[c][4] = W1[1280 + c];
        colsml[c][5] = W1[1536 + c];
    }
    if (t >= 256 && t < 320) {  // rowsml from f32 global (full precision)
        int r = t - 256;
        const float* xp = x + (b * 2048 + i0 + r) * 3;
        float xx = xp[0], xy = xp[1], xz = xp[2];
        rowsml[r][0] = sqrtf(xx * xx + xy * xy + xz * xz);
#pragma unroll
        for (int p = 0; p < 4; ++p) {
            const float* bp = basis + (b * 4 + p) * 3;
            rowsml[r][1 + p] = xx * bp[0] + xy * bp[1] + xz * bp[2];
        }
    }
    __syncthreads();

    // gen constants: chunk c = t>>2 (holds row, 8-k slice), quarter = t&3 (2 k each)
    const int gc = t >> 2, gq = t & 3;
    const int grow = ((gc >> 6) * 16) + (gc & 15);
    const int gkoff = ((gc >> 4) & 3) * 8 + gq * 2;
    const float gax = bflo((u32)xbf[i0 + grow] << 0 | 0) , gdummy = 0.f;
    // (decode via shift; written explicitly below to avoid confusion)
    const float ax = __uint_as_float(((u32)xbf[i0 + grow]) << 16);
    const float ay = __uint_as_float(((u32)xbf[2048 + i0 + grow]) << 16);
    const float az = __uint_as_float(((u32)xbf[4096 + i0 + grow]) << 16);
    (void)gax; (void)gdummy;

    auto gen = [&](int ktg, int buf) {
        int j = ktg * 32 + gkoff;   // 4 distinct u32 addrs per wave -> broadcast
        u32 xw = *(const u32*)&xbf[j];
        u32 yw = *(const u32*)&xbf[2048 + j];
        u32 zw = *(const u32*)&xbf[4096 + j];
        float d0 = ax * bflo(xw) + ay * bflo(yw) + az * bflo(zw);
        float d1 = ax * bfhi(xw) + ay * bfhi(yw) + az * bfhi(zw);
        float s0 = __builtin_amdgcn_sqrtf(d0);
        float s1 = __builtin_amdgcn_sqrtf(d1);
        ((u32*)As[buf])[t] = pack2bf(s0, s1);  // lane-consecutive u32: conflict-free
    };

    floatx4 acc[4];
    const floatx4 zero = {0.f, 0.f, 0.f, 0.f};
#pragma unroll
    for (int f = 0; f < 4; ++f) acc[f] = zero;

    gen(0, 0);
    __syncthreads();

    const u16* wfbase = W1frag + (n4 * 64 + lane) * 32;
    const int achunk = (m4 * 64 + lane) * 8;

    for (int kt = 0; kt < 64; ++kt) {
        const int buf = kt & 1;
        short8 acur = *(const short8*)&As[buf][achunk];
        const u16* bp = wfbase + kt * 8192;
        short8 bcur[4];
#pragma unroll
        for (int f = 0; f < 4; ++f) bcur[f] = *(const short8*)(bp + f * 8);
        if (kt < 63) gen(kt + 1, buf ^ 1);
#pragma unroll
        for (int f = 0; f < 4; ++f) acc[f] = mfma16(acur, bcur[f], acc[f]);
        __syncthreads();
    }

    // epilogue: small features + bias, LeakyReLU, store bf16
#pragma unroll
    for (int r = 0; r < 4; ++r) {
        int row = m4 * 16 + lq * 4 + r;
        float nrm = rowsml[row][0];
        float p0 = rowsml[row][1], p1 = rowsml[row][2];
        float p2 = rowsml[row][3], p3 = rowsml[row][4];
        u16* orow = h1 + (b * 2048 + i0 + row) * 256;
#pragma unroll
        for (int f = 0; f < 4; ++f) {
            int col = n4 * 64 + f * 16 + lr;
            float v = acc[f][r] + colsml[col][0] + nrm * colsml[col][1] +
                      p0 * colsml[col][2] + p1 * colsml[col][3] +
                      p2 * colsml[col][4] + p3 * colsml[col][5];
            v = v > 0.f ? v : 0.01f * v;
            orow[col] = f2bf(v);
        }
    }
}

// ---- fused tail: M=32 rows/block, 1024 blocks. Coalesced h1 staging -> LDS
// row-major [32][264] (528B stride: b128-aligned frag reads). h2 in LDS, then
// fk = h2@W3+b3 and x-weighted row reduce -> global atomics. Last block finalizes.
__global__ __launch_bounds__(256, 4) void k_tail(
    const u16* __restrict__ h1, const u16* __restrict__ W2frag,
    const float* __restrict__ b2, const u16* __restrict__ W3frag,
    const float* __restrict__ b3, const float* __restrict__ x,
    float* __restrict__ accum, u32* __restrict__ counter,
    float* __restrict__ out) {
    __shared__ __align__(16) u16 h1s[32][264];
    __shared__ __align__(16) u16 h2s[32][264];
    __shared__ float colb2[256];
    __shared__ float colb3[128];
    __shared__ float xs[32][4];
    __shared__ int lastblk;

    const int t = threadIdx.x;
    const int m0 = blockIdx.x * 32;
    const int b = m0 >> 11;
    const int lane = t & 63, wv = t >> 6;
    const int lr = lane & 15, lq = lane >> 4;

    colb2[t] = b2[t];
    if (t < 128) colb3[t] = b3[t];
    if (t < 32) {
        const float* xp = x + (m0 + t) * 3;
        xs[t][0] = xp[0]; xs[t][1] = xp[1]; xs[t][2] = xp[2];
    }

    // stage h1 tile: coalesced (8 lanes x 512B per row)
    {
        const int row = t >> 3, cs = (t & 7) * 32;
        const u16* src = h1 + (m0 + row) * 256 + cs;
#pragma unroll
        for (int q = 0; q < 4; ++q)
            *(uint4*)&h1s[row][cs + q * 8] = *(const uint4*)(src + q * 8);
    }
    __syncthreads();

    // ---- phase 1: h2 = lrelu(h1 @ W2 + b2)
    floatx4 acc[2][4];
    const floatx4 zero = {0.f, 0.f, 0.f, 0.f};
#pragma unroll
    for (int i = 0; i < 2; ++i)
#pragma unroll
        for (int j = 0; j < 4; ++j) acc[i][j] = zero;

    const u16* w2s = W2frag + t * 32;
#pragma unroll 2
    for (int kt = 0; kt < 8; ++kt) {
        short8 af[2], bf[4];
#pragma unroll
        for (int i = 0; i < 2; ++i)
            af[i] = *(const short8*)&h1s[i * 16 + lr][kt * 32 + lq * 8];
#pragma unroll
        for (int j = 0; j < 4; ++j)
            bf[j] = *(const short8*)(w2s + kt * 8192 + j * 8);
#pragma unroll
        for (int i = 0; i < 2; ++i)
#pragma unroll
            for (int j = 0; j < 4; ++j) acc[i][j] = mfma16(af[i], bf[j], acc[i][j]);
    }
#pragma unroll
    for (int i = 0; i < 2; ++i)
#pragma unroll
        for (int r = 0; r < 4; ++r) {
            int row = i * 16 + lq * 4 + r;
#pragma unroll
            for (int j = 0; j < 4; ++j) {
                int col = wv * 64 + j * 16 + lr;
                float v = acc[i][j][r] + colb2[col];
                v = v > 0.f ? v : 0.01f * v;
                h2s[row][col] = f2bf(v);
            }
        }
    __syncthreads();

    // ---- phase 2: fk = h2 @ W3 + b3, fused x-reduce
    floatx4 acc2[2][2];
#pragma unroll
    for (int i = 0; i < 2; ++i)
#pragma unroll
        for (int j = 0; j < 2; ++j) acc2[i][j] = zero;

    const u16* w3s = W3frag + t * 16;
#pragma unroll 2
    for (int kt = 0; kt < 8; ++kt) {
        short8 af[2], bf[2];
#pragma unroll
        for (int i = 0; i < 2; ++i)
            af[i] = *(const short8*)&h2s[i * 16 + lr][kt * 32 + lq * 8];
#pragma unroll
        for (int j = 0; j < 2; ++j)
            bf[j] = *(const short8*)(w3s + kt * 4096 + j * 8);
#pragma unroll
        for (int i = 0; i < 2; ++i)
#pragma unroll
            for (int j = 0; j < 2; ++j) acc2[i][j] = mfma16(af[i], bf[j], acc2[i][j]);
    }

    float s[2][3];
#pragma unroll
    for (int j = 0; j < 2; ++j) { s[j][0] = 0.f; s[j][1] = 0.f; s[j][2] = 0.f; }
#pragma unroll
    for (int i = 0; i < 2; ++i)
#pragma unroll
        for (int r = 0; r < 4; ++r) {
            int row = i * 16 + lq * 4 + r;
            float x0 = xs[row][0], x1 = xs[row][1], x2 = xs[row][2];
#pragma unroll
            for (int j = 0; j < 2; ++j) {
                int col = wv * 32 + j * 16 + lr;
                float fk = acc2[i][j][r] + colb3[col];
                s[j][0] += fk * x0; s[j][1] += fk * x1; s[j][2] += fk * x2;
            }
        }
#pragma unroll
    for (int j = 0; j < 2; ++j)
#pragma unroll
        for (int d = 0; d < 3; ++d) {
            float v = s[j][d];
            v += __shfl_xor(v, 16);
            v += __shfl_xor(v, 32);
            if (lane < 16) {
                int col = wv * 32 + j * 16 + lane;   // wave-exclusive cols
                atomicAdd(&accum[(b * 128 + col) * 3 + d], v);
            }
        }

    // ---- last-block finalize
    __threadfence();
    if (t == 0) {
        u32 prev = atomicAdd(counter, 1u);
        lastblk = (prev == 1023u);
    }
    __syncthreads();
    if (lastblk) {
        __threadfence();
#pragma unroll
        for (int i = 0; i < 24; ++i) {
            int idx = t + i * 256;
            float v = __hip_atomic_load(&accum[idx], __ATOMIC_RELAXED,
                                        __HIP_MEMORY_SCOPE_AGENT);
            out[idx] = v * (1.0f / 2048.0f);
        }
    }
}

extern "C" void kernel_launch(void* const* d_in, const int* in_sizes, int n_in,
                              void* d_out, int out_size, void* d_ws, size_t ws_size,
                              hipStream_t stream) {
    const float* x     = (const float*)d_in[0];
    const float* u     = (const float*)d_in[1];
    const float* basis = (const float*)d_in[2];
    const float* W1    = (const float*)d_in[3];
    const float* b1    = (const float*)d_in[4];
    const float* W2    = (const float*)d_in[5];
    const float* b2    = (const float*)d_in[6];
    const float* W3    = (const float*)d_in[7];
    const float* b3    = (const float*)d_in[8];
    float* out = (float*)d_out;

    char* ws = (char*)d_ws;
    u16*  W1frag = (u16*)ws;                      // 1,048,576 B
    u16*  W2frag = (u16*)(ws + 1048576);          //   131,072 B
    u16*  W3frag = (u16*)(ws + 1179648);          //    65,536 B
    u16*  h1     = (u16*)(ws + 1245184);          // 16,777,216 B
    float* accum = (float*)(ws + 18022400);       //    24,576 B
    u32*  counter = (u32*)(ws + 18046976);        //         4 B

    k_prep<<<81, 256, 0, stream>>>(W1, W2, W3, W1frag, W2frag, W3frag, accum, counter);
    k_h1<<<dim3(32, 16), 1024, 0, stream>>>(x, u, basis, W1, b1, W1frag, h1);
    k_tail<<<1024, 256, 0, stream>>>(h1, W2frag, b2, W3frag, b3, x, accum, counter, out);
}

// Round 9
// 280.764 us; speedup vs baseline: 1.1605x; 1.1605x over previous
//
#include <hip/hip_runtime.h>

typedef unsigned short u16;
typedef unsigned int   u32;

typedef __attribute__((ext_vector_type(8))) short short8;
typedef __attribute__((ext_vector_type(4))) float floatx4;

// ---- f32 -> bf16 (RNE) ----
__device__ __forceinline__ u16 f2bf(float f) {
    u32 u = __float_as_uint(f);
    u = u + 0x7fffu + ((u >> 16) & 1u);
    return (u16)(u >> 16);
}

__device__ __forceinline__ float bflo(u32 w) { return __uint_as_float(w << 16); }
__device__ __forceinline__ float bfhi(u32 w) { return __uint_as_float(w & 0xffff0000u); }

// pack two f32 -> two bf16 (round-to-nearest-away) in one v_perm
__device__ __forceinline__ u32 pack2bf(float s0, float s1) {
    u32 a = __float_as_uint(s0) + 0x8000u;
    u32 b = __float_as_uint(s1) + 0x8000u;
    return __builtin_amdgcn_perm(b, a, 0x07060302u);  // {bf(s1), bf(s0)}
}

__device__ __forceinline__ floatx4 mfma16(short8 a, short8 b, floatx4 c) {
    return __builtin_amdgcn_mfma_f32_16x16x32_bf16(a, b, c, 0, 0, 0);
}

// ---- prep: LDS-transpose weight tiles into per-thread MFMA B-fragment streams;
// block 80 zeroes accum + done-counter.
__global__ __launch_bounds__(256) void k_prep(
    const float* __restrict__ W1, const float* __restrict__ W2,
    const float* __restrict__ W3, u16* __restrict__ W1frag,
    u16* __restrict__ W2frag, u16* __restrict__ W3frag,
    float* __restrict__ accum, u32* __restrict__ counter) {
    __shared__ float ws[32][257];
    const int t = threadIdx.x;
    const int mode = blockIdx.x;
    const int lane = t & 63, grp = t >> 6;
    const int lr = lane & 15, lq = lane >> 4;

    if (mode < 64) {            // W1 tile kt=mode
        const int kt = mode;
#pragma unroll
        for (int i = 0; i < 32; ++i) {
            int idx2 = t + i * 256;
            ws[idx2 >> 8][idx2 & 255] = W1[(7 + kt * 32 + (idx2 >> 8)) * 256 + (idx2 & 255)];
        }
        __syncthreads();
        u16 arr[32];
#pragma unroll
        for (int f = 0; f < 4; ++f)
#pragma unroll
            for (int ji = 0; ji < 8; ++ji)
                arr[f * 8 + ji] = f2bf(ws[lq * 8 + ji][grp * 64 + f * 16 + lr]);
        uint4* dst = (uint4*)(W1frag + kt * 8192 + t * 32);
#pragma unroll
        for (int q = 0; q < 4; ++q) dst[q] = ((const uint4*)arr)[q];
    } else if (mode < 72) {     // W2 tile
        const int kt = mode - 64;
#pragma unroll
        for (int i = 0; i < 32; ++i) {
            int idx2 = t + i * 256;
            ws[idx2 >> 8][idx2 & 255] = W2[(kt * 32 + (idx2 >> 8)) * 256 + (idx2 & 255)];
        }
        __syncthreads();
        u16 arr[32];
#pragma unroll
        for (int f = 0; f < 4; ++f)
#pragma unroll
            for (int ji = 0; ji < 8; ++ji)
                arr[f * 8 + ji] = f2bf(ws[lq * 8 + ji][grp * 64 + f * 16 + lr]);
        uint4* dst = (uint4*)(W2frag + kt * 8192 + t * 32);
#pragma unroll
        for (int q = 0; q < 4; ++q) dst[q] = ((const uint4*)arr)[q];
    } else if (mode < 80) {     // W3 tile
        const int kt = mode - 72;
#pragma unroll
        for (int i = 0; i < 16; ++i) {
            int idx2 = t + i * 256;
            ws[idx2 >> 7][idx2 & 127] = W3[(kt * 32 + (idx2 >> 7)) * 128 + (idx2 & 127)];
        }
        __syncthreads();
        u16 arr[16];
#pragma unroll
        for (int j = 0; j < 2; ++j)
#pragma unroll
            for (int ji = 0; ji < 8; ++ji)
                arr[j * 8 + ji] = f2bf(ws[lq * 8 + ji][grp * 32 + j * 16 + lr]);
        uint4* dst = (uint4*)(W3frag + kt * 4096 + t * 16);
        dst[0] = ((const uint4*)arr)[0];
        dst[1] = ((const uint4*)arr)[1];
    } else {                    // zero accum + counter
#pragma unroll
        for (int i = 0; i < 24; ++i) accum[t + i * 256] = 0.f;
        if (t == 0) *counter = 0u;
    }
}

// ---- kernel 1: h1 = lrelu( [u,norm,proj,dots] @ W1 + b1 )
// 1024 thr (16 waves), M=64 x N=256 per block; wave (m4,n4) owns 16 rows x 64 cols.
// launch_bounds (1024,4): <=128 regs -> NO spills (R8's fatal mistake was (1024,8)).
// Dots tile frag-linear in LDS; gen = 2 dots/thread, lane-consecutive u32 write.
// B-fragments: per-thread global streams (L1/L2-hot) with next-kt prefetch.
__global__ __launch_bounds__(1024, 4) void k_h1(
    const float* __restrict__ x, const float* __restrict__ u,
    const float* __restrict__ basis, const float* __restrict__ W1,
    const float* __restrict__ b1, const u16* __restrict__ W1frag,
    u16* __restrict__ h1) {
    __shared__ __align__(16) u16 xbf[6144];   // 12 KB bf16 SoA: X|Y|Z
    __shared__ __align__(16) u16 As[2][2048]; // 8 KB double-buffered dots tile
    __shared__ float rowsml[64][6];
    __shared__ float colsml[256][6];

    const int t = threadIdx.x;
    const int b = blockIdx.y;
    const int i0 = blockIdx.x * 64;
    const int lane = t & 63, wv = t >> 6;
    const int lr = lane & 15, lq = lane >> 4;
    const int m4 = wv >> 2, n4 = wv & 3;

    // bf16 SoA build (coalesced float4 global read, scalar LDS scatter)
    {
        const float4* src = (const float4*)(x + b * 6144);
#pragma unroll
        for (int kk = 0; kk < 2; ++kk) {
            int q = t + kk * 1024;
            if (q < 1536) {
                float4 v = src[q];
                float vv[4] = {v.x, v.y, v.z, v.w};
                int e = q * 4;
#pragma unroll
                for (int cc = 0; cc < 4; ++cc) {
                    int ee = e + cc;
                    xbf[(ee % 3) * 2048 + ee / 3] = f2bf(vv[cc]);
                }
            }
        }
    }
    if (t < 256) {
        int c = t;
        float u0 = u[b * 2 + 0], u1 = u[b * 2 + 1];
        colsml[c][0] = b1[c] + u0 * W1[c] + u1 * W1[256 + c];
        colsml[c][1] = W1[512 + c];
        colsml[c][2] = W1[768 + c];
        colsml[c][3] = W1[1024 + c];
        colsml[c][4] = W1[1280 + c];
        colsml[c][5] = W1[1536 + c];
    }
    if (t >= 256 && t < 320) {  // rowsml from f32 global (full precision)
        int r = t - 256;
        const float* xp = x + (b * 2048 + i0 + r) * 3;
        float xx = xp[0], xy = xp[1], xz = xp[2];
        rowsml[r][0] = sqrtf(xx * xx + xy * xy + xz * xz);
#pragma unroll
        for (int p = 0; p < 4; ++p) {
            const float* bp = basis + (b * 4 + p) * 3;
            rowsml[r][1 + p] = xx * bp[0] + xy * bp[1] + xz * bp[2];
        }
    }
    __syncthreads();

    // gen constants: chunk c = t>>2 (row + 8-k slice), quarter = t&3 (2 k each)
    const int gc = t >> 2, gq = t & 3;
    const int grow = ((gc >> 6) * 16) + (gc & 15);
    const int gkoff = ((gc >> 4) & 3) * 8 + gq * 2;
    const float ax = __uint_as_float(((u32)xbf[i0 + grow]) << 16);
    const float ay = __uint_as_float(((u32)xbf[2048 + i0 + grow]) << 16);
    const float az = __uint_as_float(((u32)xbf[4096 + i0 + grow]) << 16);

    auto gen = [&](int ktg, int buf) {
        int j = ktg * 32 + gkoff;   // 4 distinct u32 addrs per wave -> broadcast
        u32 xw = *(const u32*)&xbf[j];
        u32 yw = *(const u32*)&xbf[2048 + j];
        u32 zw = *(const u32*)&xbf[4096 + j];
        float d0 = ax * bflo(xw) + ay * bflo(yw) + az * bflo(zw);
        float d1 = ax * bfhi(xw) + ay * bfhi(yw) + az * bfhi(zw);
        float s0 = __builtin_amdgcn_sqrtf(d0);
        float s1 = __builtin_amdgcn_sqrtf(d1);
        ((u32*)As[buf])[t] = pack2bf(s0, s1);  // lane-consecutive u32: conflict-free
    };

    floatx4 acc[4];
    const floatx4 zero = {0.f, 0.f, 0.f, 0.f};
#pragma unroll
    for (int f = 0; f < 4; ++f) acc[f] = zero;

    gen(0, 0);
    __syncthreads();

    const u16* wfbase = W1frag + (n4 * 64 + lane) * 32;
    const int achunk = (m4 * 64 + lane) * 8;

    short8 bcur[4], bnxt[4];
#pragma unroll
    for (int f = 0; f < 4; ++f) bcur[f] = *(const short8*)(wfbase + f * 8);

    for (int kt = 0; kt < 64; ++kt) {
        const int buf = kt & 1;
        short8 acur = *(const short8*)&As[buf][achunk];
        if (kt < 63) {
            const u16* bp = wfbase + (kt + 1) * 8192;
#pragma unroll
            for (int f = 0; f < 4; ++f) bnxt[f] = *(const short8*)(bp + f * 8);
            gen(kt + 1, buf ^ 1);
        }
#pragma unroll
        for (int f = 0; f < 4; ++f) acc[f] = mfma16(acur, bcur[f], acc[f]);
        __syncthreads();
#pragma unroll
        for (int f = 0; f < 4; ++f) bcur[f] = bnxt[f];
    }

    // epilogue: small features + bias, LeakyReLU, store bf16
#pragma unroll
    for (int r = 0; r < 4; ++r) {
        int row = m4 * 16 + lq * 4 + r;
        float nrm = rowsml[row][0];
        float p0 = rowsml[row][1], p1 = rowsml[row][2];
        float p2 = rowsml[row][3], p3 = rowsml[row][4];
        u16* orow = h1 + (b * 2048 + i0 + row) * 256;
#pragma unroll
        for (int f = 0; f < 4; ++f) {
            int col = n4 * 64 + f * 16 + lr;
            float v = acc[f][r] + colsml[col][0] + nrm * colsml[col][1] +
                      p0 * colsml[col][2] + p1 * colsml[col][3] +
                      p2 * colsml[col][4] + p3 * colsml[col][5];
            v = v > 0.f ? v : 0.01f * v;
            orow[col] = f2bf(v);
        }
    }
}

// ---- fused tail: M=32 rows/block, 1024 blocks. Coalesced h1 staging -> LDS
// [32][264]; h2 in LDS; fk = h2@W3+b3 + x-weighted reduce -> global atomics.
// Last block finalizes out = accum/2048.
__global__ __launch_bounds__(256, 4) void k_tail(
    const u16* __restrict__ h1, const u16* __restrict__ W2frag,
    const float* __restrict__ b2, const u16* __restrict__ W3frag,
    const float* __restrict__ b3, const float* __restrict__ x,
    float* __restrict__ accum, u32* __restrict__ counter,
    float* __restrict__ out) {
    __shared__ __align__(16) u16 h1s[32][264];
    __shared__ __align__(16) u16 h2s[32][264];
    __shared__ float colb2[256];
    __shared__ float colb3[128];
    __shared__ float xs[32][4];
    __shared__ int lastblk;

    const int t = threadIdx.x;
    const int m0 = blockIdx.x * 32;
    const int b = m0 >> 11;
    const int lane = t & 63, wv = t >> 6;
    const int lr = lane & 15, lq = lane >> 4;

    colb2[t] = b2[t];
    if (t < 128) colb3[t] = b3[t];
    if (t < 32) {
        const float* xp = x + (m0 + t) * 3;
        xs[t][0] = xp[0]; xs[t][1] = xp[1]; xs[t][2] = xp[2];
    }

    // stage h1 tile: coalesced (8 lanes x 512B per row)
    {
        const int row = t >> 3, cs = (t & 7) * 32;
        const u16* src = h1 + (m0 + row) * 256 + cs;
#pragma unroll
        for (int q = 0; q < 4; ++q)
            *(uint4*)&h1s[row][cs + q * 8] = *(const uint4*)(src + q * 8);
    }
    __syncthreads();

    // ---- phase 1: h2 = lrelu(h1 @ W2 + b2)
    floatx4 acc[2][4];
    const floatx4 zero = {0.f, 0.f, 0.f, 0.f};
#pragma unroll
    for (int i = 0; i < 2; ++i)
#pragma unroll
        for (int j = 0; j < 4; ++j) acc[i][j] = zero;

    const u16* w2s = W2frag + t * 32;
#pragma unroll 2
    for (int kt = 0; kt < 8; ++kt) {
        short8 af[2], bf[4];
#pragma unroll
        for (int i = 0; i < 2; ++i)
            af[i] = *(const short8*)&h1s[i * 16 + lr][kt * 32 + lq * 8];
#pragma unroll
        for (int j = 0; j < 4; ++j)
            bf[j] = *(const short8*)(w2s + kt * 8192 + j * 8);
#pragma unroll
        for (int i = 0; i < 2; ++i)
#pragma unroll
            for (int j = 0; j < 4; ++j) acc[i][j] = mfma16(af[i], bf[j], acc[i][j]);
    }
#pragma unroll
    for (int i = 0; i < 2; ++i)
#pragma unroll
        for (int r = 0; r < 4; ++r) {
            int row = i * 16 + lq * 4 + r;
#pragma unroll
            for (int j = 0; j < 4; ++j) {
                int col = wv * 64 + j * 16 + lr;
                float v = acc[i][j][r] + colb2[col];
                v = v > 0.f ? v : 0.01f * v;
                h2s[row][col] = f2bf(v);
            }
        }
    __syncthreads();

    // ---- phase 2: fk = h2 @ W3 + b3, fused x-reduce
    floatx4 acc2[2][2];
#pragma unroll
    for (int i = 0; i < 2; ++i)
#pragma unroll
        for (int j = 0; j < 2; ++j) acc2[i][j] = zero;

    const u16* w3s = W3frag + t * 16;
#pragma unroll 2
    for (int kt = 0; kt < 8; ++kt) {
        short8 af[2], bf[2];
#pragma unroll
        for (int i = 0; i < 2; ++i)
            af[i] = *(const short8*)&h2s[i * 16 + lr][kt * 32 + lq * 8];
#pragma unroll
        for (int j = 0; j < 2; ++j)
            bf[j] = *(const short8*)(w3s + kt * 4096 + j * 8);
#pragma unroll
        for (int i = 0; i < 2; ++i)
#pragma unroll
            for (int j = 0; j < 2; ++j) acc2[i][j] = mfma16(af[i], bf[j], acc2[i][j]);
    }

    float s[2][3];
#pragma unroll
    for (int j = 0; j < 2; ++j) { s[j][0] = 0.f; s[j][1] = 0.f; s[j][2] = 0.f; }
#pragma unroll
    for (int i = 0; i < 2; ++i)
#pragma unroll
        for (int r = 0; r < 4; ++r) {
            int row = i * 16 + lq * 4 + r;
            float x0 = xs[row][0], x1 = xs[row][1], x2 = xs[row][2];
#pragma unroll
            for (int j = 0; j < 2; ++j) {
                int col = wv * 32 + j * 16 + lr;
                float fk = acc2[i][j][r] + colb3[col];
                s[j][0] += fk * x0; s[j][1] += fk * x1; s[j][2] += fk * x2;
            }
        }
#pragma unroll
    for (int j = 0; j < 2; ++j)
#pragma unroll
        for (int d = 0; d < 3; ++d) {
            float v = s[j][d];
            v += __shfl_xor(v, 16);
            v += __shfl_xor(v, 32);
            if (lane < 16) {
                int col = wv * 32 + j * 16 + lane;   // wave-exclusive cols
                atomicAdd(&accum[(b * 128 + col) * 3 + d], v);
            }
        }

    // ---- last-block finalize
    __threadfence();
    if (t == 0) {
        u32 prev = atomicAdd(counter, 1u);
        lastblk = (prev == 1023u);
    }
    __syncthreads();
    if (lastblk) {
        __threadfence();
#pragma unroll
        for (int i = 0; i < 24; ++i) {
            int idx = t + i * 256;
            float v = __hip_atomic_load(&accum[idx], __ATOMIC_RELAXED,
                                        __HIP_MEMORY_SCOPE_AGENT);
            out[idx] = v * (1.0f / 2048.0f);
        }
    }
}

extern "C" void kernel_launch(void* const* d_in, const int* in_sizes, int n_in,
                              void* d_out, int out_size, void* d_ws, size_t ws_size,
                              hipStream_t stream) {
    const float* x     = (const float*)d_in[0];
    const float* u     = (const float*)d_in[1];
    const float* basis = (const float*)d_in[2];
    const float* W1    = (const float*)d_in[3];
    const float* b1    = (const float*)d_in[4];
    const float* W2    = (const float*)d_in[5];
    const float* b2    = (const float*)d_in[6];
    const float* W3    = (const float*)d_in[7];
    const float* b3    = (const float*)d_in[8];
    float* out = (float*)d_out;

    char* ws = (char*)d_ws;
    u16*  W1frag = (u16*)ws;                      // 1,048,576 B
    u16*  W2frag = (u16*)(ws + 1048576);          //   131,072 B
    u16*  W3frag = (u16*)(ws + 1179648);          //    65,536 B
    u16*  h1     = (u16*)(ws + 1245184);          // 16,777,216 B
    float* accum = (float*)(ws + 18022400);       //    24,576 B
    u32*  counter = (u32*)(ws + 18046976);        //         4 B

    k_prep<<<81, 256, 0, stream>>>(W1, W2, W3, W1frag, W2frag, W3frag, accum, counter);
    k_h1<<<dim3(32, 16), 1024, 0, stream>>>(x, u, basis, W1, b1, W1frag, h1);
    k_tail<<<1024, 256, 0, stream>>>(h1, W2frag, b2, W3frag, b3, x, accum, counter, out);
}

// Round 10
// 168.114 us; speedup vs baseline: 1.9381x; 1.6701x over previous
//
#include <hip/hip_runtime.h>

typedef unsigned short u16;
typedef unsigned int   u32;

typedef __attribute__((ext_vector_type(8))) short short8;
typedef __attribute__((ext_vector_type(4))) float floatx4;
typedef __attribute__((ext_vector_type(2))) float v2f;

// ---- f32 -> bf16 (RNE) ----
__device__ __forceinline__ u16 f2bf(float f) {
    u32 u = __float_as_uint(f);
    u = u + 0x7fffu + ((u >> 16) & 1u);
    return (u16)(u >> 16);
}

__device__ __forceinline__ float bflo(u32 w) { return __uint_as_float(w << 16); }
__device__ __forceinline__ float bfhi(u32 w) { return __uint_as_float(w & 0xffff0000u); }

// pack two f32 -> two bf16 (round-to-nearest-away) in one v_perm
__device__ __forceinline__ u32 pack2bf(float s0, float s1) {
    u32 a = __float_as_uint(s0) + 0x8000u;
    u32 b = __float_as_uint(s1) + 0x8000u;
    return __builtin_amdgcn_perm(b, a, 0x07060302u);  // {bf(s1), bf(s0)}
}

__device__ __forceinline__ floatx4 mfma16(short8 a, short8 b, floatx4 c) {
    return __builtin_amdgcn_mfma_f32_16x16x32_bf16(a, b, c, 0, 0, 0);
}

// ---- prep: LDS-transpose weight tiles into per-thread MFMA B-fragment streams;
// block 80 zeroes accum.
__global__ __launch_bounds__(256) void k_prep(
    const float* __restrict__ W1, const float* __restrict__ W2,
    const float* __restrict__ W3, u16* __restrict__ W1frag,
    u16* __restrict__ W2frag, u16* __restrict__ W3frag,
    float* __restrict__ accum) {
    __shared__ float ws[32][257];
    const int t = threadIdx.x;
    const int mode = blockIdx.x;
    const int lane = t & 63, grp = t >> 6;
    const int lr = lane & 15, lq = lane >> 4;

    if (mode < 64) {            // W1 tile kt=mode
        const int kt = mode;
#pragma unroll
        for (int i = 0; i < 32; ++i) {
            int idx2 = t + i * 256;
            ws[idx2 >> 8][idx2 & 255] = W1[(7 + kt * 32 + (idx2 >> 8)) * 256 + (idx2 & 255)];
        }
        __syncthreads();
        u16 arr[32];
#pragma unroll
        for (int f = 0; f < 4; ++f)
#pragma unroll
            for (int ji = 0; ji < 8; ++ji)
                arr[f * 8 + ji] = f2bf(ws[lq * 8 + ji][grp * 64 + f * 16 + lr]);
        uint4* dst = (uint4*)(W1frag + kt * 8192 + t * 32);
#pragma unroll
        for (int q = 0; q < 4; ++q) dst[q] = ((const uint4*)arr)[q];
    } else if (mode < 72) {     // W2 tile
        const int kt = mode - 64;
#pragma unroll
        for (int i = 0; i < 32; ++i) {
            int idx2 = t + i * 256;
            ws[idx2 >> 8][idx2 & 255] = W2[(kt * 32 + (idx2 >> 8)) * 256 + (idx2 & 255)];
        }
        __syncthreads();
        u16 arr[32];
#pragma unroll
        for (int f = 0; f < 4; ++f)
#pragma unroll
            for (int ji = 0; ji < 8; ++ji)
                arr[f * 8 + ji] = f2bf(ws[lq * 8 + ji][grp * 64 + f * 16 + lr]);
        uint4* dst = (uint4*)(W2frag + kt * 8192 + t * 32);
#pragma unroll
        for (int q = 0; q < 4; ++q) dst[q] = ((const uint4*)arr)[q];
    } else if (mode < 80) {     // W3 tile
        const int kt = mode - 72;
#pragma unroll
        for (int i = 0; i < 16; ++i) {
            int idx2 = t + i * 256;
            ws[idx2 >> 7][idx2 & 127] = W3[(kt * 32 + (idx2 >> 7)) * 128 + (idx2 & 127)];
        }
        __syncthreads();
        u16 arr[16];
#pragma unroll
        for (int j = 0; j < 2; ++j)
#pragma unroll
            for (int ji = 0; ji < 8; ++ji)
                arr[j * 8 + ji] = f2bf(ws[lq * 8 + ji][grp * 32 + j * 16 + lr]);
        uint4* dst = (uint4*)(W3frag + kt * 4096 + t * 16);
        dst[0] = ((const uint4*)arr)[0];
        dst[1] = ((const uint4*)arr)[1];
    } else {                    // zero accum
#pragma unroll
        for (int i = 0; i < 24; ++i) accum[t + i * 256] = 0.f;
    }
}

// ---- kernel 1: h1 = lrelu( [u,norm,proj,dots] @ W1 + b1 )
// BARRIER-FREE K-loop. 256 thr (4 waves, m-split): block = 256 rows x 64 cols;
// wave tile 64x64 (m4 x n4 frags, acc[4][4]). Each lane computes its OWN
// A-fragments in registers (32 dots/kt: 4 rows x 8 k), xj from LDS bf16 SoA
// (wave-uniform broadcast reads). B-frags: per-thread global streams, shared
// across the 4 m-waves at identical addresses (L1-served), prefetched 1 kt.
__global__ __launch_bounds__(256, 2) void k_h1(
    const float* __restrict__ x, const float* __restrict__ u,
    const float* __restrict__ basis, const float* __restrict__ W1,
    const float* __restrict__ b1, const u16* __restrict__ W1frag,
    u16* __restrict__ h1) {
    __shared__ __align__(16) u16 xbf[6144];   // 12 KB bf16 SoA: X|Y|Z
    __shared__ float rowsml[256][5];          // 5 KB norm+proj per block row

    const int t = threadIdx.x;
    const int h0 = blockIdx.x * 64;
    const int i0 = blockIdx.y * 256;
    const int b = blockIdx.z;
    const int lane = t & 63, wv = t >> 6;
    const int lr = lane & 15, lq = lane >> 4;
    const int strip = i0 + wv * 64;

    // stage xbf SoA (coalesced float4 read, scalar scatter)
    {
        const float4* src = (const float4*)(x + b * 6144);
#pragma unroll
        for (int i = 0; i < 6; ++i) {
            int q = t + i * 256;
            float4 v = src[q];
            float vv[4] = {v.x, v.y, v.z, v.w};
            int e = q * 4;
#pragma unroll
            for (int cc = 0; cc < 4; ++cc) {
                int ee = e + cc;
                xbf[(ee % 3) * 2048 + ee / 3] = f2bf(vv[cc]);
            }
        }
    }
    // rowsml: wave-local (row = strip + lane); same-wave read later -> no barrier dep
    {
        const float* xp = x + (b * 2048 + strip + lane) * 3;
        float xx = xp[0], xy = xp[1], xz = xp[2];
        rowsml[wv * 64 + lane][0] = sqrtf(xx * xx + xy * xy + xz * xz);
#pragma unroll
        for (int p = 0; p < 4; ++p) {
            const float* bp = basis + (b * 4 + p) * 3;
            rowsml[wv * 64 + lane][1 + p] = xx * bp[0] + xy * bp[1] + xz * bp[2];
        }
    }
    // per-lane A-row coords (4 rows: strip + i*16 + lr), f32 precision
    float axr[4], ayr[4], azr[4];
#pragma unroll
    for (int i = 0; i < 4; ++i) {
        const float* ap = x + (b * 2048 + strip + i * 16 + lr) * 3;
        axr[i] = ap[0]; ayr[i] = ap[1]; azr[i] = ap[2];
    }
    __syncthreads();   // xbf ready (the only block-wide barrier)

    floatx4 acc[4][4];
    const floatx4 zero = {0.f, 0.f, 0.f, 0.f};
#pragma unroll
    for (int i = 0; i < 4; ++i)
#pragma unroll
        for (int f = 0; f < 4; ++f) acc[i][f] = zero;

    const u16* wf = W1frag + (blockIdx.x * 64 + lane) * 32;

    short8 bcur[4], bnxt[4];
#pragma unroll
    for (int f = 0; f < 4; ++f) bcur[f] = *(const short8*)(wf + f * 8);
    uint4 xjx = *(const uint4*)&xbf[lq * 8];
    uint4 xjy = *(const uint4*)&xbf[2048 + lq * 8];
    uint4 xjz = *(const uint4*)&xbf[4096 + lq * 8];

    for (int kt = 0; kt < 64; ++kt) {
        uint4 xjxn, xjyn, xjzn;
        if (kt < 63) {
            int p = (kt + 1) * 32 + lq * 8;
            xjxn = *(const uint4*)&xbf[p];
            xjyn = *(const uint4*)&xbf[2048 + p];
            xjzn = *(const uint4*)&xbf[4096 + p];
            const u16* bp = wf + (kt + 1) * 8192;
#pragma unroll
            for (int f = 0; f < 4; ++f) bnxt[f] = *(const short8*)(bp + f * 8);
        }
        // unpack xj (8 k-points) into v2f pairs
        v2f XX[4], YY[4], ZZ[4];
        const u32* wxp = (const u32*)&xjx;
        const u32* wyp = (const u32*)&xjy;
        const u32* wzp = (const u32*)&xjz;
#pragma unroll
        for (int p = 0; p < 4; ++p) {
            XX[p][0] = bflo(wxp[p]); XX[p][1] = bfhi(wxp[p]);
            YY[p][0] = bflo(wyp[p]); YY[p][1] = bfhi(wyp[p]);
            ZZ[p][0] = bflo(wzp[p]); ZZ[p][1] = bfhi(wzp[p]);
        }
        // gen 4 A-frags in registers + 16 MFMA
        short8 afrag[4];
#pragma unroll
        for (int i = 0; i < 4; ++i) {
            v2f axv; axv[0] = axr[i]; axv[1] = axr[i];
            v2f ayv; ayv[0] = ayr[i]; ayv[1] = ayr[i];
            v2f azv; azv[0] = azr[i]; azv[1] = azr[i];
            u32 pk[4];
#pragma unroll
            for (int p = 0; p < 4; ++p) {
                v2f d = XX[p] * axv;
                d += YY[p] * ayv;
                d += ZZ[p] * azv;
                float s0 = __builtin_amdgcn_sqrtf(d[0]);
                float s1 = __builtin_amdgcn_sqrtf(d[1]);
                pk[p] = pack2bf(s0, s1);
            }
            union { uint4 u; short8 s; } cv;
            cv.u.x = pk[0]; cv.u.y = pk[1]; cv.u.z = pk[2]; cv.u.w = pk[3];
            afrag[i] = cv.s;
        }
#pragma unroll
        for (int i = 0; i < 4; ++i)
#pragma unroll
            for (int f = 0; f < 4; ++f)
                acc[i][f] = mfma16(afrag[i], bcur[f], acc[i][f]);
#pragma unroll
        for (int f = 0; f < 4; ++f) bcur[f] = bnxt[f];
        xjx = xjxn; xjy = xjyn; xjz = xjzn;
    }

    // epilogue: per-lane col features (4 cols), row features from LDS, store
    float cb[4], cn[4], c0[4], c1[4], c2[4], c3[4];
    {
        float u0 = u[b * 2 + 0], u1 = u[b * 2 + 1];
#pragma unroll
        for (int f = 0; f < 4; ++f) {
            int c = h0 + f * 16 + lr;
            cb[f] = b1[c] + u0 * W1[c] + u1 * W1[256 + c];
            cn[f] = W1[512 + c];
            c0[f] = W1[768 + c];
            c1[f] = W1[1024 + c];
            c2[f] = W1[1280 + c];
            c3[f] = W1[1536 + c];
        }
    }
#pragma unroll
    for (int i = 0; i < 4; ++i) {
#pragma unroll
        for (int r = 0; r < 4; ++r) {
            int row = i * 16 + lq * 4 + r;
            const float* rm = rowsml[wv * 64 + row];
            float nrm = rm[0], p0 = rm[1], p1 = rm[2], p2 = rm[3], p3 = rm[4];
            u16* orow = h1 + (b * 2048 + strip + row) * 256 + h0;
#pragma unroll
            for (int f = 0; f < 4; ++f) {
                float v = acc[i][f][r] + cb[f] + nrm * cn[f] +
                          p0 * c0[f] + p1 * c1[f] + p2 * c2[f] + p3 * c3[f];
                v = v > 0.f ? v : 0.01f * v;
                orow[f * 16 + lr] = f2bf(v);
            }
        }
    }
}

// ---- fused tail: M=32 rows/block, 1024 blocks. Coalesced h1 staging -> LDS;
// h2 in LDS; fk = h2@W3+b3 + x-weighted reduce -> global atomics.
__global__ __launch_bounds__(256, 4) void k_tail(
    const u16* __restrict__ h1, const u16* __restrict__ W2frag,
    const float* __restrict__ b2, const u16* __restrict__ W3frag,
    const float* __restrict__ b3, const float* __restrict__ x,
    float* __restrict__ accum) {
    __shared__ __align__(16) u16 h1s[32][264];
    __shared__ __align__(16) u16 h2s[32][264];
    __shared__ float colb2[256];
    __shared__ float colb3[128];
    __shared__ float xs[32][4];

    const int t = threadIdx.x;
    const int m0 = blockIdx.x * 32;
    const int b = m0 >> 11;
    const int lane = t & 63, wv = t >> 6;
    const int lr = lane & 15, lq = lane >> 4;

    colb2[t] = b2[t];
    if (t < 128) colb3[t] = b3[t];
    if (t < 32) {
        const float* xp = x + (m0 + t) * 3;
        xs[t][0] = xp[0]; xs[t][1] = xp[1]; xs[t][2] = xp[2];
    }

    // stage h1 tile: coalesced (8 lanes x 512B per row)
    {
        const int row = t >> 3, cs = (t & 7) * 32;
        const u16* src = h1 + (m0 + row) * 256 + cs;
#pragma unroll
        for (int q = 0; q < 4; ++q)
            *(uint4*)&h1s[row][cs + q * 8] = *(const uint4*)(src + q * 8);
    }
    __syncthreads();

    // ---- phase 1: h2 = lrelu(h1 @ W2 + b2)
    floatx4 acc[2][4];
    const floatx4 zero = {0.f, 0.f, 0.f, 0.f};
#pragma unroll
    for (int i = 0; i < 2; ++i)
#pragma unroll
        for (int j = 0; j < 4; ++j) acc[i][j] = zero;

    const u16* w2s = W2frag + t * 32;
#pragma unroll 2
    for (int kt = 0; kt < 8; ++kt) {
        short8 af[2], bf[4];
#pragma unroll
        for (int i = 0; i < 2; ++i)
            af[i] = *(const short8*)&h1s[i * 16 + lr][kt * 32 + lq * 8];
#pragma unroll
        for (int j = 0; j < 4; ++j)
            bf[j] = *(const short8*)(w2s + kt * 8192 + j * 8);
#pragma unroll
        for (int i = 0; i < 2; ++i)
#pragma unroll
            for (int j = 0; j < 4; ++j) acc[i][j] = mfma16(af[i], bf[j], acc[i][j]);
    }
#pragma unroll
    for (int i = 0; i < 2; ++i)
#pragma unroll
        for (int r = 0; r < 4; ++r) {
            int row = i * 16 + lq * 4 + r;
#pragma unroll
            for (int j = 0; j < 4; ++j) {
                int col = wv * 64 + j * 16 + lr;
                float v = acc[i][j][r] + colb2[col];
                v = v > 0.f ? v : 0.01f * v;
                h2s[row][col] = f2bf(v);
            }
        }
    __syncthreads();

    // ---- phase 2: fk = h2 @ W3 + b3, fused x-reduce
    floatx4 acc2[2][2];
#pragma unroll
    for (int i = 0; i < 2; ++i)
#pragma unroll
        for (int j = 0; j < 2; ++j) acc2[i][j] = zero;

    const u16* w3s = W3frag + t * 16;
#pragma unroll 2
    for (int kt = 0; kt < 8; ++kt) {
        short8 af[2], bf[2];
#pragma unroll
        for (int i = 0; i < 2; ++i)
            af[i] = *(const short8*)&h2s[i * 16 + lr][kt * 32 + lq * 8];
#pragma unroll
        for (int j = 0; j < 2; ++j)
            bf[j] = *(const short8*)(w3s + kt * 4096 + j * 8);
#pragma unroll
        for (int i = 0; i < 2; ++i)
#pragma unroll
            for (int j = 0; j < 2; ++j) acc2[i][j] = mfma16(af[i], bf[j], acc2[i][j]);
    }

    float s[2][3];
#pragma unroll
    for (int j = 0; j < 2; ++j) { s[j][0] = 0.f; s[j][1] = 0.f; s[j][2] = 0.f; }
#pragma unroll
    for (int i = 0; i < 2; ++i)
#pragma unroll
        for (int r = 0; r < 4; ++r) {
            int row = i * 16 + lq * 4 + r;
            float x0 = xs[row][0], x1 = xs[row][1], x2 = xs[row][2];
#pragma unroll
            for (int j = 0; j < 2; ++j) {
                int col = wv * 32 + j * 16 + lr;
                float fk = acc2[i][j][r] + colb3[col];
                s[j][0] += fk * x0; s[j][1] += fk * x1; s[j][2] += fk * x2;
            }
        }
#pragma unroll
    for (int j = 0; j < 2; ++j)
#pragma unroll
        for (int d = 0; d < 3; ++d) {
            float v = s[j][d];
            v += __shfl_xor(v, 16);
            v += __shfl_xor(v, 32);
            if (lane < 16) {
                int col = wv * 32 + j * 16 + lane;   // wave-exclusive cols
                atomicAdd(&accum[(b * 128 + col) * 3 + d], v);
            }
        }
}

__global__ void k_fin(const float* __restrict__ accum, float* __restrict__ out) {
    int idx = blockIdx.x * 256 + threadIdx.x;
    if (idx < 6144) out[idx] = accum[idx] * (1.0f / 2048.0f);
}

extern "C" void kernel_launch(void* const* d_in, const int* in_sizes, int n_in,
                              void* d_out, int out_size, void* d_ws, size_t ws_size,
                              hipStream_t stream) {
    const float* x     = (const float*)d_in[0];
    const float* u     = (const float*)d_in[1];
    const float* basis = (const float*)d_in[2];
    const float* W1    = (const float*)d_in[3];
    const float* b1    = (const float*)d_in[4];
    const float* W2    = (const float*)d_in[5];
    const float* b2    = (const float*)d_in[6];
    const float* W3    = (const float*)d_in[7];
    const float* b3    = (const float*)d_in[8];
    float* out = (float*)d_out;

    char* ws = (char*)d_ws;
    u16*  W1frag = (u16*)ws;                      // 1,048,576 B
    u16*  W2frag = (u16*)(ws + 1048576);          //   131,072 B
    u16*  W3frag = (u16*)(ws + 1179648);          //    65,536 B
    u16*  h1     = (u16*)(ws + 1245184);          // 16,777,216 B
    float* accum = (float*)(ws + 18022400);       //    24,576 B

    k_prep<<<81, 256, 0, stream>>>(W1, W2, W3, W1frag, W2frag, W3frag, accum);
    k_h1<<<dim3(4, 8, 16), 256, 0, stream>>>(x, u, basis, W1, b1, W1frag, h1);
    k_tail<<<1024, 256, 0, stream>>>(h1, W2frag, b2, W3frag, b3, x, accum);
    k_fin<<<24, 256, 0, stream>>>(accum, out);
}